// Round 4
// baseline (6644.644 us; speedup 1.0000x reference)
//
#include <hip/hip_runtime.h>
#include <math.h>

#define B_   256
#define N_   1536
#define OBS_ 20
#define HOR_ 30

typedef __bf16 bf16;
typedef bf16  bf16x8 __attribute__((ext_vector_type(8)));
typedef float f32x4  __attribute__((ext_vector_type(4)));

// ---------------------------------------------------------------------------
// fp32 tiled GEMM (prologue only): C = A@B + colBias, optional bf16 copy.
// ---------------------------------------------------------------------------
__global__ __launch_bounds__(256) void gemm_k(
    const float* __restrict__ A, int lda,
    const float* __restrict__ Bw, int ldb,
    float* __restrict__ C, bf16* __restrict__ Cb, int ldc,
    int K, const float* __restrict__ colBias)
{
    __shared__ float As[16][68];
    __shared__ float Bs[16][68];
    const int tid = threadIdx.x;
    const int tx = tid & 15, ty = tid >> 4;
    const int n0 = blockIdx.y * 64, j0 = blockIdx.x * 64;
    float acc[4][4] = {};
    const int a_kk = tid & 15, a_nn0 = tid >> 4;
    const int b_jj = tid & 63, b_kk0 = tid >> 6;
    for (int k0 = 0; k0 < K; k0 += 16) {
#pragma unroll
        for (int i = 0; i < 4; i++) {
            int nn = a_nn0 + 16 * i;
            As[a_kk][nn] = (k0 + a_kk < K) ? A[(size_t)(n0 + nn) * lda + k0 + a_kk] : 0.f;
        }
#pragma unroll
        for (int i = 0; i < 4; i++) {
            int kk = b_kk0 + 4 * i;
            Bs[kk][b_jj] = (k0 + kk < K) ? Bw[(size_t)(k0 + kk) * ldb + j0 + b_jj] : 0.f;
        }
        __syncthreads();
#pragma unroll
        for (int kk = 0; kk < 16; kk++) {
            float4 av = *(const float4*)&As[kk][ty * 4];
            float4 bv = *(const float4*)&Bs[kk][tx * 4];
            float aa[4] = {av.x, av.y, av.z, av.w};
            float bb[4] = {bv.x, bv.y, bv.z, bv.w};
#pragma unroll
            for (int i = 0; i < 4; i++)
#pragma unroll
                for (int j = 0; j < 4; j++) acc[i][j] += aa[i] * bb[j];
        }
        __syncthreads();
    }
#pragma unroll
    for (int i = 0; i < 4; i++) {
        int n = n0 + ty * 4 + i;
#pragma unroll
        for (int j = 0; j < 4; j++) {
            int jj = j0 + tx * 4 + j;
            float v = acc[i][j];
            if (colBias) v += colBias[jj];
            if (C)  C[(size_t)n * ldc + jj] = v;
            if (Cb) Cb[(size_t)n * ldc + jj] = (bf16)v;
        }
    }
}

// ---------------------------------------------------------------------------
// Pack B[K][J] (fp32 or bf16, row-major ld=lds, rows>=srcRows zero) into
// MFMA-fragment order: dst[((jg*KC+kc)*64+lane)*8+i] = B[kc*32+(lane>>4)*8+i][jg*16+(lane&15)]
// ---------------------------------------------------------------------------
__global__ void pack_k(const float* __restrict__ srcF, const bf16* __restrict__ srcB,
                       int srcRows, int KC, int J, int lds, bf16* __restrict__ dst)
{
    int idx = blockIdx.x * 256 + threadIdx.x;
    int total = (J / 16) * KC * 64;
    if (idx >= total) return;
    int lane = idx & 63;
    int kc = (idx >> 6) % KC;
    int jg = idx / (64 * KC);
    int k0 = kc * 32 + (lane >> 4) * 8;
    int col = jg * 16 + (lane & 15);
    bf16x8 v;
#pragma unroll
    for (int i = 0; i < 8; i++) {
        int r = k0 + i;
        float x = 0.f;
        if (r < srcRows) x = srcF ? srcF[(size_t)r * lds + col] : (float)srcB[(size_t)r * lds + col];
        v[i] = (bf16)x;
    }
    *(bf16x8*)&dst[(size_t)idx * 8] = v;
}

// ---------------------------------------------------------------------------
__global__ __launch_bounds__(256) void emb_obs_k(
    const float* __restrict__ obs, const float* __restrict__ Wemb,
    const float* __restrict__ bemb, float* __restrict__ emb_obs)
{
    int tid = blockIdx.x * 256 + threadIdx.x;
    if (tid >= OBS_ * B_ * 32) return;
    int r = tid >> 5, e = tid & 31;
    float v = obs[r * 2] * Wemb[e] + obs[r * 2 + 1] * Wemb[32 + e] + bemb[e];
    emb_obs[tid] = fmaxf(v, 0.f);
}

// Weff[r, h*32+c] = sum_d Wqkv[r, h*64+d] * Wqkv[c, 512+h*64+d]; r=512 row = bias_qp.
__global__ __launch_bounds__(256) void weff_k(
    const float* __restrict__ Wqkv, const float* __restrict__ bqkv,
    float* __restrict__ Weff)
{
    __shared__ float qrow[512];
    const int r = blockIdx.x;
    const int t = threadIdx.x;
    for (int j = t; j < 512; j += 256)
        qrow[j] = (r < 512) ? Wqkv[(size_t)r * 1536 + j] : bqkv[j];
    __syncthreads();
    const int h = t >> 5, c = t & 31;
    float acc = 0.f;
#pragma unroll 8
    for (int d = 0; d < 64; d++)
        acc += qrow[h * 64 + d] * Wqkv[(size_t)c * 1536 + 512 + h * 64 + d];
    Weff[(size_t)r * 256 + t] = acc;
}

// WovCat[h*32+c, j] = sum_d Wqkv[c, 1024+h*64+d] * W_o[h*64+d, j]  (rows 0..255)
__global__ __launch_bounds__(256) void wov_k(
    const float* __restrict__ Wqkv, const float* __restrict__ Wo,
    bf16* __restrict__ WovCat)
{
    __shared__ float vrow[64];
    const int row = blockIdx.x;
    const int h = row >> 5, c = row & 31;
    const int t = threadIdx.x;
    if (t < 64) vrow[t] = Wqkv[(size_t)c * 1536 + 1024 + h * 64 + t];
    __syncthreads();
    for (int j = t; j < 512; j += 256) {
        float acc = 0.f;
#pragma unroll 8
        for (int d = 0; d < 64; d++)
            acc += vrow[d] * Wo[(size_t)(h * 64 + d) * 512 + j];
        WovCat[(size_t)row * 512 + j] = (bf16)acc;
    }
}

// ---------------------------------------------------------------------------
// Attention (unchanged from R3): ec -> ecA1b[:,0:256] bf16.
// ---------------------------------------------------------------------------
__global__ __launch_bounds__(256) void attn_k(
    const float* __restrict__ qp, const float* __restrict__ emb_obs,
    const float* __restrict__ emb_gen, bf16* __restrict__ ecA1b, int t)
{
    __shared__ float qp_s[256];
    __shared__ float emb_s[50 * 33];
    __shared__ float at_s[4][64];
    const int n = blockIdx.x, b = n / 6, tid = threadIdx.x;
    qp_s[tid] = qp[(size_t)n * 256 + tid];
    for (int idx = tid; idx < t * 32; idx += 256) {
        int l = idx >> 5, c = idx & 31;
        emb_s[l * 33 + c] = (l < OBS_) ? emb_obs[((size_t)l * B_ + b) * 32 + c]
                                       : emb_gen[((size_t)(l - OBS_) * N_ + n) * 32 + c];
    }
    __syncthreads();
    const int w = tid >> 6, lane = tid & 63;
#pragma unroll
    for (int hh = 0; hh < 2; hh++) {
        const int h = w * 2 + hh;
        float sc = -1e30f;
        if (lane < t) {
            float s_ = 0.f;
#pragma unroll 8
            for (int c = 0; c < 32; c++) s_ += emb_s[lane * 33 + c] * qp_s[h * 32 + c];
            sc = s_ * 0.125f;
        }
        float mx = sc;
#pragma unroll
        for (int o = 32; o > 0; o >>= 1) mx = fmaxf(mx, __shfl_xor(mx, o, 64));
        float e = (lane < t) ? __expf(sc - mx) : 0.f;
        float sm = e;
#pragma unroll
        for (int o = 32; o > 0; o >>= 1) sm += __shfl_xor(sm, o, 64);
        at_s[w][lane] = e / sm;
        if (lane < 32) {
            float ec = 0.f;
            for (int l = 0; l < t; l++) ec += at_s[w][l] * emb_s[l * 33 + lane];
            ecA1b[(size_t)n * 288 + h * 32 + lane] = (bf16)ec;
        }
    }
}

// ---------------------------------------------------------------------------
// K2: a-GEMM (K=288, J=512) + LN1 fused. Block = 16 rows; grid 96.
// acc += [ec|extras]@Wov; v = acc + featvO[b][j] + x_last[j]; h1 = LN(v).
// ---------------------------------------------------------------------------
__global__ __launch_bounds__(256) void aln1_k(
    const bf16* __restrict__ ecA1b, const bf16* __restrict__ Bp,
    const float* __restrict__ featvO, const float* __restrict__ A1f,
    const float* __restrict__ feat, const float* __restrict__ g1,
    const float* __restrict__ bt1, float* __restrict__ h1f, bf16* __restrict__ h1b)
{
    __shared__ float hs[16][520];
    __shared__ float stats[16][2];
    const int n0 = blockIdx.x * 16;
    const int tid = threadIdx.x;
    const int w = tid >> 6, lane = tid & 63;
    const int quad = lane >> 4, m15 = lane & 15;
    f32x4 acc[8] = {};
    const int KC = 9;
    for (int kc = 0; kc < KC; kc++) {
        bf16x8 af = *(const bf16x8*)&ecA1b[(size_t)(n0 + m15) * 288 + kc * 32 + quad * 8];
#pragma unroll
        for (int g = 0; g < 8; g++) {
            int jg = w * 8 + g;
            bf16x8 bfr = *(const bf16x8*)&Bp[((size_t)(jg * KC + kc) * 64 + lane) * 8];
            acc[g] = __builtin_amdgcn_mfma_f32_16x16x32_bf16(af, bfr, acc[g], 0, 0, 0);
        }
    }
#pragma unroll
    for (int g = 0; g < 8; g++) {
        int j = (w * 8 + g) * 16 + m15;
#pragma unroll
        for (int r = 0; r < 4; r++) {
            int row = quad * 4 + r, n = n0 + row, b = n / 6;
            float x = (j < 64) ? A1f[(size_t)n * 64 + j] : feat[(size_t)b * 448 + (j - 64)];
            hs[row][j] = acc[g][r] + featvO[(size_t)b * 512 + j] + x;
        }
    }
    __syncthreads();
#pragma unroll
    for (int rr = 0; rr < 4; rr++) {
        int row = w * 4 + rr;
        float s = 0.f, sq = 0.f;
#pragma unroll
        for (int i = 0; i < 8; i++) { float v = hs[row][lane + i * 64]; s += v; sq += v * v; }
#pragma unroll
        for (int o = 32; o > 0; o >>= 1) { s += __shfl_xor(s, o, 64); sq += __shfl_xor(sq, o, 64); }
        if (lane == 0) {
            float mu = s * (1.f / 512.f);
            float var = sq * (1.f / 512.f) - mu * mu;
            stats[row][0] = mu; stats[row][1] = rsqrtf(var + 1e-5f);
        }
    }
    __syncthreads();
#pragma unroll
    for (int i = 0; i < 32; i++) {
        int idx = tid + i * 256;
        int row = idx >> 9, j = idx & 511;
        float v = (hs[row][j] - stats[row][0]) * stats[row][1] * g1[j] + bt1[j];
        h1f[(size_t)(n0 + row) * 512 + j] = v;
        h1b[(size_t)(n0 + row) * 512 + j] = (bf16)v;
    }
}

// ---------------------------------------------------------------------------
// K3: FF1 (K=512, J=2048), relu, bf16 out. Block = 16 rows x 1024 cols; grid (2,96).
// ---------------------------------------------------------------------------
__global__ __launch_bounds__(256) void ff1_k(
    const bf16* __restrict__ h1b, const bf16* __restrict__ Bp,
    const float* __restrict__ bff1, bf16* __restrict__ f1b)
{
    const int n0 = blockIdx.y * 16;
    const int jb = blockIdx.x;   // 0/1
    const int tid = threadIdx.x;
    const int w = tid >> 6, lane = tid & 63;
    const int quad = lane >> 4, m15 = lane & 15;
    f32x4 acc[16] = {};
    const int KC = 16;
    for (int kc = 0; kc < KC; kc++) {
        bf16x8 af = *(const bf16x8*)&h1b[(size_t)(n0 + m15) * 512 + kc * 32 + quad * 8];
#pragma unroll
        for (int g = 0; g < 16; g++) {
            int jg = jb * 64 + w * 16 + g;
            bf16x8 bfr = *(const bf16x8*)&Bp[((size_t)(jg * KC + kc) * 64 + lane) * 8];
            acc[g] = __builtin_amdgcn_mfma_f32_16x16x32_bf16(af, bfr, acc[g], 0, 0, 0);
        }
    }
#pragma unroll
    for (int g = 0; g < 16; g++) {
        int j = (jb * 64 + w * 16 + g) * 16 + m15;
#pragma unroll
        for (int r = 0; r < 4; r++) {
            int n = n0 + quad * 4 + r;
            f1b[(size_t)n * 2048 + j] = (bf16)fmaxf(acc[g][r] + bff1[j], 0.f);
        }
    }
}

// ---------------------------------------------------------------------------
// K4: FF2 (K=2048, J=512) + LN2 fused -> h2p bf16 (ld 544). Block = 16 rows; grid 96.
// ---------------------------------------------------------------------------
__global__ __launch_bounds__(256) void ff2ln2_k(
    const bf16* __restrict__ f1b, const bf16* __restrict__ Bp,
    const float* __restrict__ bff2, const float* __restrict__ h1f,
    const float* __restrict__ g2, const float* __restrict__ bt2,
    const float* __restrict__ small5, bf16* __restrict__ h2p)
{
    __shared__ float hs[16][520];
    __shared__ float stats[16][2];
    const int n0 = blockIdx.x * 16;
    const int tid = threadIdx.x;
    const int w = tid >> 6, lane = tid & 63;
    const int quad = lane >> 4, m15 = lane & 15;
    f32x4 acc[8] = {};
    const int KC = 64;
    for (int kc = 0; kc < KC; kc++) {
        bf16x8 af = *(const bf16x8*)&f1b[(size_t)(n0 + m15) * 2048 + kc * 32 + quad * 8];
#pragma unroll
        for (int g = 0; g < 8; g++) {
            int jg = w * 8 + g;
            bf16x8 bfr = *(const bf16x8*)&Bp[((size_t)(jg * KC + kc) * 64 + lane) * 8];
            acc[g] = __builtin_amdgcn_mfma_f32_16x16x32_bf16(af, bfr, acc[g], 0, 0, 0);
        }
    }
#pragma unroll
    for (int g = 0; g < 8; g++) {
        int j = (w * 8 + g) * 16 + m15;
#pragma unroll
        for (int r = 0; r < 4; r++) {
            int row = quad * 4 + r, n = n0 + row;
            hs[row][j] = acc[g][r] + bff2[j] + h1f[(size_t)n * 512 + j];
        }
    }
    __syncthreads();
#pragma unroll
    for (int rr = 0; rr < 4; rr++) {
        int row = w * 4 + rr;
        float s = 0.f, sq = 0.f;
#pragma unroll
        for (int i = 0; i < 8; i++) { float v = hs[row][lane + i * 64]; s += v; sq += v * v; }
#pragma unroll
        for (int o = 32; o > 0; o >>= 1) { s += __shfl_xor(s, o, 64); sq += __shfl_xor(sq, o, 64); }
        if (lane == 0) {
            float mu = s * (1.f / 512.f);
            float var = sq * (1.f / 512.f) - mu * mu;
            stats[row][0] = mu; stats[row][1] = rsqrtf(var + 1e-5f);
        }
    }
    __syncthreads();
#pragma unroll
    for (int i = 0; i < 32; i++) {
        int idx = tid + i * 256;
        int row = idx >> 9, j = idx & 511;
        float v = (hs[row][j] - stats[row][0]) * stats[row][1] * g2[j] + bt2[j];
        h2p[(size_t)(n0 + row) * 544 + j] = (bf16)v;
    }
    if (tid < 16) {
        int n = n0 + tid;
        for (int c = 512; c < 544; c++)
            h2p[(size_t)n * 544 + c] = (c < 519) ? (bf16)small5[n * 8 + (c - 512)] : (bf16)0.f;
    }
}

// ---------------------------------------------------------------------------
// K5: fus-GEMM (K=544, J=448) + out-proj + next-state. Block = 16 rows; grid 96.
// ---------------------------------------------------------------------------
__global__ __launch_bounds__(256) void fusfin_k(
    const bf16* __restrict__ h2p, const bf16* __restrict__ Bp,
    const float* __restrict__ feat_fus, const float* __restrict__ Wout,
    const float* __restrict__ bout, const float* __restrict__ Wemb,
    const float* __restrict__ bemb, const float* __restrict__ loc,
    const float* __restrict__ Weff, const float* __restrict__ featqp,
    float* __restrict__ dout, float* __restrict__ emb_gen,
    float* __restrict__ A1f, bf16* __restrict__ ecA1b,
    float* __restrict__ small5, float* __restrict__ qp, int s)
{
    __shared__ float fus[16][452];
    __shared__ float osh[16][2];
    __shared__ float A1s[16][64];
    const int n0 = blockIdx.x * 16;
    const int tid = threadIdx.x;
    const int w = tid >> 6, lane = tid & 63;
    const int quad = lane >> 4, m15 = lane & 15;
    f32x4 acc[7] = {};
    const int KC = 17;
    for (int kc = 0; kc < KC; kc++) {
        bf16x8 af = *(const bf16x8*)&h2p[(size_t)(n0 + m15) * 544 + kc * 32 + quad * 8];
#pragma unroll
        for (int g = 0; g < 7; g++) {
            int jg = w * 7 + g;
            bf16x8 bfr = *(const bf16x8*)&Bp[((size_t)(jg * KC + kc) * 64 + lane) * 8];
            acc[g] = __builtin_amdgcn_mfma_f32_16x16x32_bf16(af, bfr, acc[g], 0, 0, 0);
        }
    }
#pragma unroll
    for (int g = 0; g < 7; g++) {
        int j = (w * 7 + g) * 16 + m15;
#pragma unroll
        for (int r = 0; r < 4; r++) {
            int row = quad * 4 + r, n = n0 + row, b = n / 6;
            fus[row][j] = acc[g][r] + feat_fus[(size_t)b * 448 + j];
        }
    }
    __syncthreads();
#pragma unroll
    for (int rr = 0; rr < 4; rr++) {
        int row = w * 4 + rr;
        float p0 = 0.f, p1 = 0.f;
#pragma unroll
        for (int i = 0; i < 7; i++) {
            int j = lane + i * 64;
            float f = fus[row][j];
            p0 += f * Wout[j * 2];
            p1 += f * Wout[j * 2 + 1];
        }
#pragma unroll
        for (int o = 32; o > 0; o >>= 1) { p0 += __shfl_xor(p0, o, 64); p1 += __shfl_xor(p1, o, 64); }
        if (lane == 0) {
            float o0 = p0 + bout[0], o1 = p1 + bout[1];
            osh[row][0] = o0; osh[row][1] = o1;
            int n = n0 + row, b = n / 6, m = n % 6;
            dout[(size_t)b * 360 + m * 60 + s * 2]     = o0;
            dout[(size_t)b * 360 + m * 60 + s * 2 + 1] = o1;
        }
    }
    __syncthreads();
    // next-state assembly: thread t handles row r=t>>4, cols (t&15)+16i
    {
        int r = tid >> 4, c0 = tid & 15;
        int n = n0 + r, b = n / 6, m = n % 6;
        float o0 = osh[r][0], o1 = osh[r][1];
        float g0 = loc[b * 12 + m * 2], g1 = loc[b * 12 + m * 2 + 1];
        float d0 = g0 - o0, d1 = g1 - o1;
        float tc = (float)(OBS_ + s + 1);
#pragma unroll
        for (int i = 0; i < 4; i++) {
            int c = c0 + 16 * i;
            float v;
            if (c < 32) {
                v = fmaxf(o0 * Wemb[c] + o1 * Wemb[32 + c] + bemb[c], 0.f);
                emb_gen[((size_t)s * N_ + n) * 32 + c] = v;
            } else {
                int cc = c - 32;
                if      (cc < 8)  v = (cc & 1) ? g1 : g0;
                else if (cc < 16) v = (cc & 1) ? o1 : o0;
                else if (cc < 24) v = (cc & 1) ? d1 : d0;
                else              v = tc;
                ecA1b[(size_t)n * 288 + 256 + cc] = (bf16)v;
            }
            A1s[r][c] = v;
            A1f[(size_t)n * 64 + c] = v;
        }
        if (c0 < 7) {
            float v2 = (c0==0)?o0:(c0==1)?o1:(c0==2)?g0:(c0==3)?g1:(c0==4)?d0:(c0==5)?d1:tc;
            small5[n * 8 + c0] = v2;
        }
    }
    __syncthreads();
    // qp = featqp[b] + A1s @ Weff : thread t -> row r, cols c0+16cc
    {
        int r = tid >> 4, c0 = tid & 15;
        int n = n0 + r, b = n / 6;
#pragma unroll
        for (int cc = 0; cc < 16; cc++) {
            int col = c0 + cc * 16;
            float acc2 = featqp[(size_t)b * 256 + col];
#pragma unroll 8
            for (int k = 0; k < 64; k++) acc2 += A1s[r][k] * Weff[k * 256 + col];
            qp[(size_t)n * 256 + col] = acc2;
        }
    }
}

__global__ __launch_bounds__(256) void init_k(
    const float* __restrict__ obs, const float* __restrict__ emb_obs,
    const float* __restrict__ loc, const float* __restrict__ Weff,
    const float* __restrict__ featqp,
    float* __restrict__ A1f, bf16* __restrict__ ecA1b,
    float* __restrict__ small5, float* __restrict__ qp)
{
    __shared__ float A1s[64];
    const int n = blockIdx.x, b = n / 6, m = n % 6, t = threadIdx.x;
    float o0 = obs[(19 * B_ + b) * 2], o1 = obs[(19 * B_ + b) * 2 + 1];
    float g0 = loc[b * 12 + m * 2], g1 = loc[b * 12 + m * 2 + 1];
    if (t < 32) {
        A1s[t] = emb_obs[((size_t)19 * B_ + b) * 32 + t];
    } else if (t < 64) {
        int c = t - 32; float d0 = g0 - o0, d1 = g1 - o1; float tc = 20.f;
        float v;
        if      (c < 8)  v = (c & 1) ? g1 : g0;
        else if (c < 16) v = (c & 1) ? o1 : o0;
        else if (c < 24) v = (c & 1) ? d1 : d0;
        else             v = tc;
        A1s[t] = v;
    }
    if (t < 7) {
        float d0 = g0 - o0, d1 = g1 - o1; float tc = 20.f;
        float v2 = (t==0)?o0:(t==1)?o1:(t==2)?g0:(t==3)?g1:(t==4)?d0:(t==5)?d1:tc;
        small5[n * 8 + t] = v2;
    }
    __syncthreads();
    if (t < 64) {
        A1f[(size_t)n * 64 + t] = A1s[t];
        if (t >= 32) ecA1b[(size_t)n * 288 + 256 + (t - 32)] = (bf16)A1s[t];
    }
    float acc = featqp[(size_t)b * 256 + t];
#pragma unroll 8
    for (int k = 0; k < 64; k++) acc += A1s[k] * Weff[k * 256 + t];
    qp[(size_t)n * 256 + t] = acc;
}

// ---------------------------------------------------------------------------
extern "C" void kernel_launch(void* const* d_in, const int* in_sizes, int n_in,
                              void* d_out_, int out_size, void* d_ws, size_t ws_size,
                              hipStream_t stream) {
    (void)in_sizes; (void)n_in; (void)out_size; (void)ws_size;
    const float* feat  = (const float*)d_in[0];
    const float* loc   = (const float*)d_in[1];
    const float* obs   = (const float*)d_in[2];
    const float* W_emb = (const float*)d_in[3];
    const float* b_emb = (const float*)d_in[4];
    const float* W_qkv = (const float*)d_in[5];
    const float* b_qkv = (const float*)d_in[6];
    const float* W_o   = (const float*)d_in[7];
    const float* b_o   = (const float*)d_in[8];
    const float* W_ff1 = (const float*)d_in[9];
    const float* b_ff1 = (const float*)d_in[10];
    const float* W_ff2 = (const float*)d_in[11];
    const float* b_ff2 = (const float*)d_in[12];
    const float* ln1_g = (const float*)d_in[13];
    const float* ln1_b = (const float*)d_in[14];
    const float* ln2_g = (const float*)d_in[15];
    const float* ln2_b = (const float*)d_in[16];
    const float* W_fus = (const float*)d_in[17];
    const float* b_fus = (const float*)d_in[18];
    const float* W_out = (const float*)d_in[19];
    const float* b_out = (const float*)d_in[20];
    float* dout = (float*)d_out_;

    float* ws = (float*)d_ws;
    float* Weff     = ws; ws += 513 * 256;
    float* featqp   = ws; ws += 256 * 256;
    float* featv    = ws; ws += 256 * 512;
    float* featvO   = ws; ws += 256 * 512;
    float* feat_fus = ws; ws += 256 * 448;
    float* emb_obs  = ws; ws += OBS_ * B_ * 32;
    float* emb_gen  = ws; ws += HOR_ * N_ * 32;
    float* qp       = ws; ws += (size_t)N_ * 256;
    float* A1f      = ws; ws += (size_t)N_ * 64;
    float* small5   = ws; ws += (size_t)N_ * 8;
    float* h1f      = ws; ws += (size_t)N_ * 512;
    bf16* WovCat = (bf16*)ws; ws += (320 * 512) / 2;
    bf16* BpA    = (bf16*)ws; ws += (32 * 9 * 512) / 2;     // 512 cols, KC=9
    bf16* BpF1   = (bf16*)ws; ws += (128 * 16 * 512) / 2;   // 2048 cols, KC=16
    bf16* BpF2   = (bf16*)ws; ws += (32 * 64 * 512) / 2;    // 512 cols, KC=64
    bf16* BpFus  = (bf16*)ws; ws += (28 * 17 * 512) / 2;    // 448 cols, KC=17
    bf16* ecA1b  = (bf16*)ws; ws += ((size_t)N_ * 288) / 2;
    bf16* h1b    = (bf16*)ws; ws += ((size_t)N_ * 512) / 2;
    bf16* f1b    = (bf16*)ws; ws += ((size_t)N_ * 2048) / 2;
    bf16* h2p    = (bf16*)ws; ws += ((size_t)N_ * 544) / 2;

    // ---- prologue ----
    emb_obs_k<<<dim3(640), dim3(256), 0, stream>>>(obs, W_emb, b_emb, emb_obs);
    weff_k<<<dim3(513), dim3(256), 0, stream>>>(W_qkv, b_qkv, Weff);
    gemm_k<<<dim3(4, 4), dim3(256), 0, stream>>>(feat, 448, Weff + 64 * 256, 256,
        featqp, nullptr, 256, 448, Weff + 512 * 256);
    wov_k<<<dim3(256), dim3(256), 0, stream>>>(W_qkv, W_o, WovCat);
    gemm_k<<<dim3(8, 4), dim3(256), 0, stream>>>(feat, 448, W_qkv + 64 * 1536 + 1024, 1536,
        featv, nullptr, 512, 448, b_qkv + 1024);
    gemm_k<<<dim3(8, 4), dim3(256), 0, stream>>>(featv, 512, W_o, 512,
        featvO, nullptr, 512, 512, b_o);
    gemm_k<<<dim3(8, 1), dim3(256), 0, stream>>>(W_qkv + 32 * 1536 + 1024, 1536, W_o, 512,
        featv, WovCat + 256 * 512, 512, 512, nullptr);
    gemm_k<<<dim3(7, 4), dim3(256), 0, stream>>>(feat, 448, W_fus + 519 * 448, 448,
        feat_fus, nullptr, 448, 448, b_fus);
    // fragment-order packs
    pack_k<<<dim3(72),  dim3(256), 0, stream>>>(nullptr, WovCat, 288, 9,  512,  512,  BpA);
    pack_k<<<dim3(512), dim3(256), 0, stream>>>(W_ff1, nullptr, 512, 16, 2048, 2048, BpF1);
    pack_k<<<dim3(512), dim3(256), 0, stream>>>(W_ff2, nullptr, 2048, 64, 512, 512,  BpF2);
    pack_k<<<dim3(120), dim3(256), 0, stream>>>(W_fus, nullptr, 519, 17, 448,  448,  BpFus);
    init_k<<<dim3(N_), dim3(256), 0, stream>>>(obs, emb_obs, loc, Weff, featqp,
        A1f, ecA1b, small5, qp);

    // ---- 30 sequential decode steps, 5 kernels each ----
    for (int s = 0; s < HOR_; s++) {
        attn_k<<<dim3(N_), dim3(256), 0, stream>>>(qp, emb_obs, emb_gen, ecA1b, OBS_ + s);
        aln1_k<<<dim3(96), dim3(256), 0, stream>>>(ecA1b, BpA, featvO, A1f, feat,
            ln1_g, ln1_b, h1f, h1b);
        ff1_k<<<dim3(2, 96), dim3(256), 0, stream>>>(h1b, BpF1, b_ff1, f1b);
        ff2ln2_k<<<dim3(96), dim3(256), 0, stream>>>(f1b, BpF2, b_ff2, h1f,
            ln2_g, ln2_b, small5, h2p);
        fusfin_k<<<dim3(96), dim3(256), 0, stream>>>(h2p, BpFus, feat_fus, W_out, b_out,
            W_emb, b_emb, loc, Weff, featqp, dout, emb_gen, A1f, ecA1b, small5, qp, s);
    }
}

// Round 5
// 2937.640 us; speedup vs baseline: 2.2619x; 2.2619x over previous
//
#include <hip/hip_runtime.h>
#include <math.h>

#define B_   256
#define N_   1536
#define OBS_ 20
#define HOR_ 30

typedef __bf16 bf16;
typedef bf16  bf16x8 __attribute__((ext_vector_type(8)));
typedef float f32x4  __attribute__((ext_vector_type(4)));

// ---------------------------------------------------------------------------
// fp32 tiled GEMM (prologue only): C = A@B + colBias, optional bf16 copy.
// ---------------------------------------------------------------------------
__global__ __launch_bounds__(256) void gemm_k(
    const float* __restrict__ A, int lda,
    const float* __restrict__ Bw, int ldb,
    float* __restrict__ C, bf16* __restrict__ Cb, int ldc,
    int K, const float* __restrict__ colBias)
{
    __shared__ float As[16][68];
    __shared__ float Bs[16][68];
    const int tid = threadIdx.x;
    const int tx = tid & 15, ty = tid >> 4;
    const int n0 = blockIdx.y * 64, j0 = blockIdx.x * 64;
    float acc[4][4] = {};
    const int a_kk = tid & 15, a_nn0 = tid >> 4;
    const int b_jj = tid & 63, b_kk0 = tid >> 6;
    for (int k0 = 0; k0 < K; k0 += 16) {
#pragma unroll
        for (int i = 0; i < 4; i++) {
            int nn = a_nn0 + 16 * i;
            As[a_kk][nn] = (k0 + a_kk < K) ? A[(size_t)(n0 + nn) * lda + k0 + a_kk] : 0.f;
        }
#pragma unroll
        for (int i = 0; i < 4; i++) {
            int kk = b_kk0 + 4 * i;
            Bs[kk][b_jj] = (k0 + kk < K) ? Bw[(size_t)(k0 + kk) * ldb + j0 + b_jj] : 0.f;
        }
        __syncthreads();
#pragma unroll
        for (int kk = 0; kk < 16; kk++) {
            float4 av = *(const float4*)&As[kk][ty * 4];
            float4 bv = *(const float4*)&Bs[kk][tx * 4];
            float aa[4] = {av.x, av.y, av.z, av.w};
            float bb[4] = {bv.x, bv.y, bv.z, bv.w};
#pragma unroll
            for (int i = 0; i < 4; i++)
#pragma unroll
                for (int j = 0; j < 4; j++) acc[i][j] += aa[i] * bb[j];
        }
        __syncthreads();
    }
#pragma unroll
    for (int i = 0; i < 4; i++) {
        int n = n0 + ty * 4 + i;
#pragma unroll
        for (int j = 0; j < 4; j++) {
            int jj = j0 + tx * 4 + j;
            float v = acc[i][j];
            if (colBias) v += colBias[jj];
            if (C)  C[(size_t)n * ldc + jj] = v;
            if (Cb) Cb[(size_t)n * ldc + jj] = (bf16)v;
        }
    }
}

// ---------------------------------------------------------------------------
// Pack B[K][J] into MFMA-fragment order:
// dst[((jg*KC+kc)*64+lane)*8+i] = B[kc*32+(lane>>4)*8+i][jg*16+(lane&15)]
// ---------------------------------------------------------------------------
__global__ void pack_k(const float* __restrict__ srcF, const bf16* __restrict__ srcB,
                       int srcRows, int KC, int J, int lds, bf16* __restrict__ dst)
{
    int idx = blockIdx.x * 256 + threadIdx.x;
    int total = (J / 16) * KC * 64;
    if (idx >= total) return;
    int lane = idx & 63;
    int kc = (idx >> 6) % KC;
    int jg = idx / (64 * KC);
    int k0 = kc * 32 + (lane >> 4) * 8;
    int col = jg * 16 + (lane & 15);
    bf16x8 v;
#pragma unroll
    for (int i = 0; i < 8; i++) {
        int r = k0 + i;
        float x = 0.f;
        if (r < srcRows) x = srcF ? srcF[(size_t)r * lds + col] : (float)srcB[(size_t)r * lds + col];
        v[i] = (bf16)x;
    }
    *(bf16x8*)&dst[(size_t)idx * 8] = v;
}

// ---------------------------------------------------------------------------
// Fast MFMA GEMM, no LDS, prepacked B. Tile 32 rows x 64 cols; block = 256
// (4 waves: wave w -> rows (w&1)*16, j-groups (w>>1)*2 .. +1).
// grid (J/64, Nrows/32). KC = K/32 compile-time.
// ---------------------------------------------------------------------------
template<int KC>
__global__ __launch_bounds__(256) void fgemm_k(
    const bf16* __restrict__ A, int lda,
    const bf16* __restrict__ Bp,
    float* __restrict__ C, bf16* __restrict__ Cb, int ldc,
    const float* __restrict__ colBias,
    const float* __restrict__ rowMat, int ldRm,
    int doRelu)
{
    const int n0 = blockIdx.y * 32;
    const int j0g = blockIdx.x * 4;
    const int tid = threadIdx.x;
    const int w = tid >> 6, lane = tid & 63;
    const int quad = lane >> 4, m15 = lane & 15;
    const int r0 = (w & 1) * 16;
    const int cg = (w >> 1) * 2;
    const bf16* Arow = &A[(size_t)(n0 + r0 + m15) * lda + quad * 8];
    const bf16* B0 = &Bp[((size_t)(j0g + cg) * KC * 64 + lane) * 8];
    const bf16* B1 = &Bp[((size_t)(j0g + cg + 1) * KC * 64 + lane) * 8];
    f32x4 acc0 = {}, acc1 = {};
#pragma unroll 8
    for (int kc = 0; kc < KC; kc++) {
        bf16x8 af = *(const bf16x8*)&Arow[kc * 32];
        bf16x8 b0 = *(const bf16x8*)&B0[(size_t)kc * 512];
        bf16x8 b1 = *(const bf16x8*)&B1[(size_t)kc * 512];
        acc0 = __builtin_amdgcn_mfma_f32_16x16x32_bf16(af, b0, acc0, 0, 0, 0);
        acc1 = __builtin_amdgcn_mfma_f32_16x16x32_bf16(af, b1, acc1, 0, 0, 0);
    }
#pragma unroll
    for (int g = 0; g < 2; g++) {
        f32x4 a = g ? acc1 : acc0;
        int j = (j0g + cg + g) * 16 + m15;
        float cb = colBias ? colBias[j] : 0.f;
#pragma unroll
        for (int r = 0; r < 4; r++) {
            int n = n0 + r0 + quad * 4 + r;
            float v = a[r] + cb;
            if (rowMat) v += rowMat[(size_t)(n / 6) * ldRm + j];
            if (doRelu) v = fmaxf(v, 0.f);
            if (C)  C[(size_t)n * ldc + j] = v;
            if (Cb) Cb[(size_t)n * ldc + j] = (bf16)v;
        }
    }
}

// ---------------------------------------------------------------------------
__global__ __launch_bounds__(256) void emb_obs_k(
    const float* __restrict__ obs, const float* __restrict__ Wemb,
    const float* __restrict__ bemb, float* __restrict__ emb_obs)
{
    int tid = blockIdx.x * 256 + threadIdx.x;
    if (tid >= OBS_ * B_ * 32) return;
    int r = tid >> 5, e = tid & 31;
    float v = obs[r * 2] * Wemb[e] + obs[r * 2 + 1] * Wemb[32 + e] + bemb[e];
    emb_obs[tid] = fmaxf(v, 0.f);
}

// Weff[r, h*32+c] = sum_d Wqkv[r, h*64+d] * Wqkv[c, 512+h*64+d]; r=512 row = bias_qp.
__global__ __launch_bounds__(256) void weff_k(
    const float* __restrict__ Wqkv, const float* __restrict__ bqkv,
    float* __restrict__ Weff)
{
    __shared__ float qrow[512];
    const int r = blockIdx.x;
    const int t = threadIdx.x;
    for (int j = t; j < 512; j += 256)
        qrow[j] = (r < 512) ? Wqkv[(size_t)r * 1536 + j] : bqkv[j];
    __syncthreads();
    const int h = t >> 5, c = t & 31;
    float acc = 0.f;
#pragma unroll 8
    for (int d = 0; d < 64; d++)
        acc += qrow[h * 64 + d] * Wqkv[(size_t)c * 1536 + 512 + h * 64 + d];
    Weff[(size_t)r * 256 + t] = acc;
}

// WovCat[h*32+c, j] = sum_d Wqkv[c, 1024+h*64+d] * W_o[h*64+d, j]  (rows 0..255)
__global__ __launch_bounds__(256) void wov_k(
    const float* __restrict__ Wqkv, const float* __restrict__ Wo,
    bf16* __restrict__ WovCat)
{
    __shared__ float vrow[64];
    const int row = blockIdx.x;
    const int h = row >> 5, c = row & 31;
    const int t = threadIdx.x;
    if (t < 64) vrow[t] = Wqkv[(size_t)c * 1536 + 1024 + h * 64 + t];
    __syncthreads();
    for (int j = t; j < 512; j += 256) {
        float acc = 0.f;
#pragma unroll 8
        for (int d = 0; d < 64; d++)
            acc += vrow[d] * Wo[(size_t)(h * 64 + d) * 512 + j];
        WovCat[(size_t)row * 512 + j] = (bf16)acc;
    }
}

// ---------------------------------------------------------------------------
// Attention: scores = 0.125 * qp . emb[l]; ec -> ecA1b[:,0:256] bf16.
// ---------------------------------------------------------------------------
__global__ __launch_bounds__(256) void attn_k(
    const float* __restrict__ qp, const float* __restrict__ emb_obs,
    const float* __restrict__ emb_gen, bf16* __restrict__ ecA1b, int t)
{
    __shared__ float qp_s[256];
    __shared__ float emb_s[50 * 33];
    __shared__ float at_s[4][64];
    const int n = blockIdx.x, b = n / 6, tid = threadIdx.x;
    qp_s[tid] = qp[(size_t)n * 256 + tid];
    for (int idx = tid; idx < t * 32; idx += 256) {
        int l = idx >> 5, c = idx & 31;
        emb_s[l * 33 + c] = (l < OBS_) ? emb_obs[((size_t)l * B_ + b) * 32 + c]
                                       : emb_gen[((size_t)(l - OBS_) * N_ + n) * 32 + c];
    }
    __syncthreads();
    const int w = tid >> 6, lane = tid & 63;
#pragma unroll
    for (int hh = 0; hh < 2; hh++) {
        const int h = w * 2 + hh;
        float sc = -1e30f;
        if (lane < t) {
            float s_ = 0.f;
#pragma unroll 8
            for (int c = 0; c < 32; c++) s_ += emb_s[lane * 33 + c] * qp_s[h * 32 + c];
            sc = s_ * 0.125f;
        }
        float mx = sc;
#pragma unroll
        for (int o = 32; o > 0; o >>= 1) mx = fmaxf(mx, __shfl_xor(mx, o, 64));
        float e = (lane < t) ? __expf(sc - mx) : 0.f;
        float sm = e;
#pragma unroll
        for (int o = 32; o > 0; o >>= 1) sm += __shfl_xor(sm, o, 64);
        at_s[w][lane] = e / sm;
        if (lane < 32) {
            float ec = 0.f;
            for (int l = 0; l < t; l++) ec += at_s[w][l] * emb_s[l * 33 + lane];
            ecA1b[(size_t)n * 288 + h * 32 + lane] = (bf16)ec;
        }
    }
}

// ---------------------------------------------------------------------------
// LN1: h1 = LN([A1f|feat] + a) -> h1f fp32 + h1b bf16. grid N x 256.
// ---------------------------------------------------------------------------
__global__ __launch_bounds__(256) void ln1_k(
    const float* __restrict__ a, const float* __restrict__ A1f,
    const float* __restrict__ feat, const float* __restrict__ g,
    const float* __restrict__ bt, float* __restrict__ h1f, bf16* __restrict__ h1b)
{
    __shared__ float red[8];
    const int n = blockIdx.x, b = n / 6, tid = threadIdx.x;
    float r[2]; float s = 0.f, sq = 0.f;
#pragma unroll
    for (int i = 0; i < 2; i++) {
        int j = tid + i * 256;
        float x = (j < 64) ? A1f[(size_t)n * 64 + j] : feat[(size_t)b * 448 + (j - 64)];
        float v = a[(size_t)n * 512 + j] + x;
        r[i] = v; s += v; sq += v * v;
    }
#pragma unroll
    for (int o = 32; o > 0; o >>= 1) { s += __shfl_xor(s, o, 64); sq += __shfl_xor(sq, o, 64); }
    int w = tid >> 6, lane = tid & 63;
    if (lane == 0) { red[w] = s; red[4 + w] = sq; }
    __syncthreads();
    s  = red[0] + red[1] + red[2] + red[3];
    sq = red[4] + red[5] + red[6] + red[7];
    float mu = s * (1.f / 512.f);
    float var = sq * (1.f / 512.f) - mu * mu;
    float rs = rsqrtf(var + 1e-5f);
#pragma unroll
    for (int i = 0; i < 2; i++) {
        int j = tid + i * 256;
        float v = (r[i] - mu) * rs * g[j] + bt[j];
        h1f[(size_t)n * 512 + j] = v;
        h1b[(size_t)n * 512 + j] = (bf16)v;
    }
}

// ---------------------------------------------------------------------------
// LN2: h2p = [LN(h1+ff) | small5 | zeros] as bf16, ld 544. grid N x 256.
// ---------------------------------------------------------------------------
__global__ __launch_bounds__(256) void ln2_k(
    const float* __restrict__ h1, const float* __restrict__ ff,
    const float* __restrict__ g, const float* __restrict__ bt,
    const float* __restrict__ small5, bf16* __restrict__ h2p)
{
    __shared__ float red[8];
    const int n = blockIdx.x, tid = threadIdx.x;
    float r[2]; float s = 0.f, sq = 0.f;
#pragma unroll
    for (int i = 0; i < 2; i++) {
        int j = tid + i * 256;
        float v = h1[(size_t)n * 512 + j] + ff[(size_t)n * 512 + j];
        r[i] = v; s += v; sq += v * v;
    }
#pragma unroll
    for (int o = 32; o > 0; o >>= 1) { s += __shfl_xor(s, o, 64); sq += __shfl_xor(sq, o, 64); }
    int w = tid >> 6, lane = tid & 63;
    if (lane == 0) { red[w] = s; red[4 + w] = sq; }
    __syncthreads();
    s  = red[0] + red[1] + red[2] + red[3];
    sq = red[4] + red[5] + red[6] + red[7];
    float mu = s * (1.f / 512.f);
    float var = sq * (1.f / 512.f) - mu * mu;
    float rs = rsqrtf(var + 1e-5f);
#pragma unroll
    for (int i = 0; i < 2; i++) {
        int j = tid + i * 256;
        h2p[(size_t)n * 544 + j] = (bf16)((r[i] - mu) * rs * g[j] + bt[j]);
    }
    if (tid < 7)  h2p[(size_t)n * 544 + 512 + tid] = (bf16)small5[n * 8 + tid];
    if (tid < 25) h2p[(size_t)n * 544 + 519 + tid] = (bf16)0.f;
}

// ---------------------------------------------------------------------------
// Next-state producer (shared logic)
// ---------------------------------------------------------------------------
__device__ __forceinline__ void next_state(
    int n, int b, int t, float o0, float o1, float g0, float g1, float tc,
    const float* Wemb, const float* bemb, const float* Weff, const float* featqp,
    float* emb_dst, float* A1f, bf16* ecA1b, float* small5, float* qp, float* A1s)
{
    float d0 = g0 - o0, d1 = g1 - o1;
    if (t < 32) {
        float e = fmaxf(o0 * Wemb[t] + o1 * Wemb[32 + t] + bemb[t], 0.f);
        if (emb_dst) emb_dst[t] = e;
        A1s[t] = e;
    } else if (t < 64) {
        int c = t - 32;
        float v;
        if      (c < 8)  v = (c & 1) ? g1 : g0;
        else if (c < 16) v = (c & 1) ? o1 : o0;
        else if (c < 24) v = (c & 1) ? d1 : d0;
        else             v = tc;
        A1s[t] = v;
    }
    if (t < 7) {
        float v2 = (t==0)?o0:(t==1)?o1:(t==2)?g0:(t==3)?g1:(t==4)?d0:(t==5)?d1:tc;
        small5[n * 8 + t] = v2;
    }
    __syncthreads();
    if (t < 64) {
        A1f[(size_t)n * 64 + t] = A1s[t];
        if (t >= 32) ecA1b[(size_t)n * 288 + 256 + (t - 32)] = (bf16)A1s[t];
    }
    float acc = featqp[(size_t)b * 256 + t];
#pragma unroll 8
    for (int k = 0; k < 64; k++) acc += A1s[k] * Weff[k * 256 + t];
    qp[(size_t)n * 256 + t] = acc;
}

__global__ __launch_bounds__(256) void init_k(
    const float* __restrict__ obs, const float* __restrict__ emb_obs,
    const float* __restrict__ loc, const float* __restrict__ Weff,
    const float* __restrict__ featqp,
    float* __restrict__ A1f, bf16* __restrict__ ecA1b,
    float* __restrict__ small5, float* __restrict__ qp)
{
    __shared__ float A1s[64];
    const int n = blockIdx.x, b = n / 6, m = n % 6, t = threadIdx.x;
    float o0 = obs[(19 * B_ + b) * 2], o1 = obs[(19 * B_ + b) * 2 + 1];
    float g0 = loc[b * 12 + m * 2], g1 = loc[b * 12 + m * 2 + 1];
    if (t < 32) {
        A1s[t] = emb_obs[((size_t)19 * B_ + b) * 32 + t];
    } else if (t < 64) {
        int c = t - 32; float d0 = g0 - o0, d1 = g1 - o1; float tc = 20.f;
        float v;
        if      (c < 8)  v = (c & 1) ? g1 : g0;
        else if (c < 16) v = (c & 1) ? o1 : o0;
        else if (c < 24) v = (c & 1) ? d1 : d0;
        else             v = tc;
        A1s[t] = v;
    }
    if (t < 7) {
        float d0 = g0 - o0, d1 = g1 - o1; float tc = 20.f;
        float v2 = (t==0)?o0:(t==1)?o1:(t==2)?g0:(t==3)?g1:(t==4)?d0:(t==5)?d1:tc;
        small5[n * 8 + t] = v2;
    }
    __syncthreads();
    if (t < 64) {
        A1f[(size_t)n * 64 + t] = A1s[t];
        if (t >= 32) ecA1b[(size_t)n * 288 + 256 + (t - 32)] = (bf16)A1s[t];
    }
    float acc = featqp[(size_t)b * 256 + t];
#pragma unroll 8
    for (int k = 0; k < 64; k++) acc += A1s[k] * Weff[k * 256 + t];
    qp[(size_t)n * 256 + t] = acc;
}

// ---------------------------------------------------------------------------
// finish: out = fusv@W_out + b_out -> dout; then produce step s+1 state.
// grid N, block 256. Threads cover all 448 fus elements (t and t+256).
// ---------------------------------------------------------------------------
__global__ __launch_bounds__(256) void finish_k(
    const float* __restrict__ fusv, const float* __restrict__ Wout,
    const float* __restrict__ bout, const float* __restrict__ Wemb,
    const float* __restrict__ bemb, const float* __restrict__ loc,
    const float* __restrict__ Weff, const float* __restrict__ featqp,
    float* __restrict__ dout, float* __restrict__ emb_gen,
    float* __restrict__ A1f, bf16* __restrict__ ecA1b,
    float* __restrict__ small5, float* __restrict__ qp, int s)
{
    __shared__ float red[8];
    __shared__ float osh[2];
    __shared__ float A1s[64];
    const int n = blockIdx.x, b = n / 6, m = n % 6, t = threadIdx.x;
    float f0 = fusv[(size_t)n * 448 + t];
    float p0 = f0 * Wout[t * 2];
    float p1 = f0 * Wout[t * 2 + 1];
    if (t < 192) {
        float f1 = fusv[(size_t)n * 448 + 256 + t];
        p0 += f1 * Wout[(256 + t) * 2];
        p1 += f1 * Wout[(256 + t) * 2 + 1];
    }
#pragma unroll
    for (int o = 32; o > 0; o >>= 1) { p0 += __shfl_xor(p0, o, 64); p1 += __shfl_xor(p1, o, 64); }
    int w = t >> 6, lane = t & 63;
    if (lane == 0) { red[w] = p0; red[4 + w] = p1; }
    __syncthreads();
    if (t == 0) {
        float o0 = red[0] + red[1] + red[2] + red[3] + bout[0];
        float o1 = red[4] + red[5] + red[6] + red[7] + bout[1];
        osh[0] = o0; osh[1] = o1;
        dout[(size_t)b * 360 + m * 60 + s * 2]     = o0;
        dout[(size_t)b * 360 + m * 60 + s * 2 + 1] = o1;
    }
    __syncthreads();
    float o0 = osh[0], o1 = osh[1];
    float g0 = loc[b * 12 + m * 2], g1 = loc[b * 12 + m * 2 + 1];
    next_state(n, b, t, o0, o1, g0, g1, (float)(OBS_ + s + 1),
               Wemb, bemb, Weff, featqp,
               &emb_gen[((size_t)s * N_ + n) * 32], A1f, ecA1b, small5, qp, A1s);
}

// ---------------------------------------------------------------------------
extern "C" void kernel_launch(void* const* d_in, const int* in_sizes, int n_in,
                              void* d_out_, int out_size, void* d_ws, size_t ws_size,
                              hipStream_t stream) {
    (void)in_sizes; (void)n_in; (void)out_size; (void)ws_size;
    const float* feat  = (const float*)d_in[0];
    const float* loc   = (const float*)d_in[1];
    const float* obs   = (const float*)d_in[2];
    const float* W_emb = (const float*)d_in[3];
    const float* b_emb = (const float*)d_in[4];
    const float* W_qkv = (const float*)d_in[5];
    const float* b_qkv = (const float*)d_in[6];
    const float* W_o   = (const float*)d_in[7];
    const float* b_o   = (const float*)d_in[8];
    const float* W_ff1 = (const float*)d_in[9];
    const float* b_ff1 = (const float*)d_in[10];
    const float* W_ff2 = (const float*)d_in[11];
    const float* b_ff2 = (const float*)d_in[12];
    const float* ln1_g = (const float*)d_in[13];
    const float* ln1_b = (const float*)d_in[14];
    const float* ln2_g = (const float*)d_in[15];
    const float* ln2_b = (const float*)d_in[16];
    const float* W_fus = (const float*)d_in[17];
    const float* b_fus = (const float*)d_in[18];
    const float* W_out = (const float*)d_in[19];
    const float* b_out = (const float*)d_in[20];
    float* dout = (float*)d_out_;

    float* ws = (float*)d_ws;
    float* Weff     = ws; ws += 513 * 256;
    float* featqp   = ws; ws += 256 * 256;
    float* featv    = ws; ws += 256 * 512;
    float* featvO   = ws; ws += 256 * 512;
    float* feat_fus = ws; ws += 256 * 448;
    float* emb_obs  = ws; ws += OBS_ * B_ * 32;
    float* emb_gen  = ws; ws += HOR_ * N_ * 32;
    float* qp       = ws; ws += (size_t)N_ * 256;
    float* A1f      = ws; ws += (size_t)N_ * 64;
    float* small5   = ws; ws += (size_t)N_ * 8;
    float* h1f      = ws; ws += (size_t)N_ * 512;
    float* aF       = ws; ws += (size_t)N_ * 512;
    float* ffB      = ws; ws += (size_t)N_ * 512;
    float* fusv     = ws; ws += (size_t)N_ * 448;
    bf16* WovCat = (bf16*)ws; ws += (320 * 512) / 2;
    bf16* BpA    = (bf16*)ws; ws += (32 * 9 * 512) / 2;     // 512 cols, KC=9
    bf16* BpF1   = (bf16*)ws; ws += (128 * 16 * 512) / 2;   // 2048 cols, KC=16
    bf16* BpF2   = (bf16*)ws; ws += (32 * 64 * 512) / 2;    // 512 cols, KC=64
    bf16* BpFus  = (bf16*)ws; ws += (28 * 17 * 512) / 2;    // 448 cols, KC=17
    bf16* ecA1b  = (bf16*)ws; ws += ((size_t)N_ * 288) / 2;
    bf16* h1b    = (bf16*)ws; ws += ((size_t)N_ * 512) / 2;
    bf16* f1b    = (bf16*)ws; ws += ((size_t)N_ * 2048) / 2;
    bf16* h2p    = (bf16*)ws; ws += ((size_t)N_ * 544) / 2;

    // ---- prologue ----
    emb_obs_k<<<dim3(640), dim3(256), 0, stream>>>(obs, W_emb, b_emb, emb_obs);
    weff_k<<<dim3(513), dim3(256), 0, stream>>>(W_qkv, b_qkv, Weff);
    gemm_k<<<dim3(4, 4), dim3(256), 0, stream>>>(feat, 448, Weff + 64 * 256, 256,
        featqp, nullptr, 256, 448, Weff + 512 * 256);
    wov_k<<<dim3(256), dim3(256), 0, stream>>>(W_qkv, W_o, WovCat);
    gemm_k<<<dim3(8, 4), dim3(256), 0, stream>>>(feat, 448, W_qkv + 64 * 1536 + 1024, 1536,
        featv, nullptr, 512, 448, b_qkv + 1024);
    gemm_k<<<dim3(8, 4), dim3(256), 0, stream>>>(featv, 512, W_o, 512,
        featvO, nullptr, 512, 512, b_o);
    gemm_k<<<dim3(8, 1), dim3(256), 0, stream>>>(W_qkv + 32 * 1536 + 1024, 1536, W_o, 512,
        featv, WovCat + 256 * 512, 512, 512, nullptr);
    gemm_k<<<dim3(7, 4), dim3(256), 0, stream>>>(feat, 448, W_fus + 519 * 448, 448,
        feat_fus, nullptr, 448, 448, b_fus);
    pack_k<<<dim3(72),  dim3(256), 0, stream>>>(nullptr, WovCat, 288, 9,  512,  512,  BpA);
    pack_k<<<dim3(512), dim3(256), 0, stream>>>(W_ff1, nullptr, 512, 16, 2048, 2048, BpF1);
    pack_k<<<dim3(512), dim3(256), 0, stream>>>(W_ff2, nullptr, 2048, 64, 512, 512,  BpF2);
    pack_k<<<dim3(120), dim3(256), 0, stream>>>(W_fus, nullptr, 519, 17, 448,  448,  BpFus);
    init_k<<<dim3(N_), dim3(256), 0, stream>>>(obs, emb_obs, loc, Weff, featqp,
        A1f, ecA1b, small5, qp);

    // ---- 30 sequential decode steps, 8 kernels each ----
    for (int s = 0; s < HOR_; s++) {
        attn_k<<<dim3(N_), dim3(256), 0, stream>>>(qp, emb_obs, emb_gen, ecA1b, OBS_ + s);
        // a = [ec|extras] @ WovCat + featvO[b]
        fgemm_k<9><<<dim3(8, 48), dim3(256), 0, stream>>>(ecA1b, 288, BpA,
            aF, nullptr, 512, nullptr, featvO, 512, 0);
        ln1_k<<<dim3(N_), dim3(256), 0, stream>>>(aF, A1f, feat, ln1_g, ln1_b, h1f, h1b);
        // f1 = relu(h1 @ W_ff1 + b_ff1)
        fgemm_k<16><<<dim3(32, 48), dim3(256), 0, stream>>>(h1b, 512, BpF1,
            nullptr, f1b, 2048, b_ff1, nullptr, 0, 1);
        // ff = f1 @ W_ff2 + b_ff2
        fgemm_k<64><<<dim3(8, 48), dim3(256), 0, stream>>>(f1b, 2048, BpF2,
            ffB, nullptr, 512, b_ff2, nullptr, 0, 0);
        ln2_k<<<dim3(N_), dim3(256), 0, stream>>>(h1f, ffB, ln2_g, ln2_b, small5, h2p);
        // fusv = h2p @ W_fus[0:519] + feat_fus[b]
        fgemm_k<17><<<dim3(7, 48), dim3(256), 0, stream>>>(h2p, 544, BpFus,
            fusv, nullptr, 448, nullptr, feat_fus, 448, 0);
        finish_k<<<dim3(N_), dim3(256), 0, stream>>>(fusv, W_out, b_out, W_emb, b_emb,
            loc, Weff, featqp, dout, emb_gen, A1f, ecA1b, small5, qp, s);
    }
}